// Round 6
// baseline (259.925 us; speedup 1.0000x reference)
//
#include <hip/hip_runtime.h>
#include <math.h>

// SimpleGCN R18: R13 chassis (edge-parallel bucketed agg, PASSED correctness)
// with the one mechanism fix + epilogue repair.
//  - R13 post-mortem: LDS *float* atomicAdd = CAS loop (361us, VALU 3.7%).
//    LDS *int* atomicAdd is native ds_add_u32. Accumulate fixed-point int32,
//    scale 2^21 (|sum| <= ~120 -> 2.5e8 << 2^31; quant err ~2e-5 << bf16
//    rounding already in pipeline). Self-loop + bias stay fp32 (exact).
//  - R13's GEMM2 epilogue used per-thread wcol[64] (scratch; VGPR=52<64
//    proves spill). Now: Ws staged in LDS (fm-swizzled rows), per-wave
//    16-row register tile acc2[16], b128 h-broadcast reads.
//  - R17 post-mortem (wave-gather lineage dead): in-flight = waves x depth
//    is invariant under node-per-wave splits; edge-parallel streaming is
//    the only structure that raises MLP.
//  - 7 dispatches: hist, scan, scatter, dinv_gemm, agg1, agg2, readout.

#define CH 4096
#define MAXNB 1024
#define SCL 2097152.0f            // 2^21
#define INVSCL 4.76837158203125e-7f

__device__ __forceinline__ float bf2f(unsigned short u) {
    return __uint_as_float(((unsigned)u) << 16);
}
__device__ __forceinline__ unsigned short f2bf(float x) {
    unsigned b = __float_as_uint(x);
    return (unsigned short)((b + 0x7FFF + ((b >> 16) & 1)) >> 16);  // RNE
}

__global__ __launch_bounds__(256) void k_bucket_hist(const int* __restrict__ dst,
                                                     int* __restrict__ histmat,
                                                     int E, int NB) {
    __shared__ int ih[MAXNB];
    int t = threadIdx.x;
    for (int k = t; k < NB; k += 256) ih[k] = 0;
    __syncthreads();
    int base = blockIdx.x * CH;
    for (int i = 0; i < CH; i += 256) {
        int e = base + i + t;
        if (e < E) atomicAdd(&ih[dst[e] >> 6], 1);
    }
    __syncthreads();
    for (int k = t; k < NB; k += 256) histmat[(size_t)blockIdx.x * NB + k] = ih[k];
}

// ONE block, 1024 threads: per-bucket exclusive prefix over chunks (in-place,
// coalesced, unroll-8), in-LDS scan of bucket totals -> bstart; zero gpart.
__global__ __launch_bounds__(1024) void k_scan(int* __restrict__ histmat,
                                               int* __restrict__ bstart,
                                               float* __restrict__ gpart,
                                               int NB, int nch, int E) {
    __shared__ int sc[1024];
    int t = threadIdx.x;
    int run = 0;
    if (t < NB) {
        int b = 0;
        for (; b + 8 <= nch; b += 8) {
            int v[8];
#pragma unroll
            for (int u = 0; u < 8; u++) v[u] = histmat[(size_t)(b + u) * NB + t];
#pragma unroll
            for (int u = 0; u < 8; u++) {
                int x = v[u];
                histmat[(size_t)(b + u) * NB + t] = run;
                run += x;
            }
        }
        for (; b < nch; b++) {
            int x = histmat[(size_t)b * NB + t];
            histmat[(size_t)b * NB + t] = run;
            run += x;
        }
    }
    sc[t] = (t < NB) ? run : 0;
    __syncthreads();
    for (int off = 1; off < 1024; off <<= 1) {
        int x = (t >= off) ? sc[t - off] : 0;
        __syncthreads();
        sc[t] += x;
        __syncthreads();
    }
    if (t < NB) bstart[t] = sc[t] - run;  // exclusive
    if (t == 0) bstart[NB] = E;
    if (t < 512) gpart[t] = 0.f;
}

__global__ __launch_bounds__(256) void k_bucket_scatter(const int* __restrict__ src,
                                                        const int* __restrict__ dst,
                                                        const int* __restrict__ histmat,
                                                        const int* __restrict__ bstart,
                                                        int* __restrict__ staged,
                                                        int E, int NB) {
    __shared__ int cur[MAXNB];
    int t = threadIdx.x;
    for (int k = t; k < NB; k += 256)
        cur[k] = bstart[k] + histmat[(size_t)blockIdx.x * NB + k];
    __syncthreads();
    int base = blockIdx.x * CH;
    for (int i = 0; i < CH; i += 256) {
        int e = base + i + t;
        if (e < E) {
            int d = dst[e];
            int pos = atomicAdd(&cur[d >> 6], 1);
            staged[pos] = (src[e] << 6) | (d & 63);  // n<=65536 -> fits
        }
    }
}

// Per-bucket: degrees from staged slab -> dinv; 64-row GEMM1 tile (R13-proven).
__global__ __launch_bounds__(256) void k_dinv_gemm(const float* __restrict__ X,
                                                   const float* __restrict__ W1,
                                                   const int* __restrict__ staged,
                                                   const int* __restrict__ bstart,
                                                   float* __restrict__ dinv,
                                                   unsigned short* __restrict__ Y, int n) {
    __shared__ float Ws[64 * 64];
    __shared__ float xs[16][64];
    __shared__ int cnt[64];
    __shared__ float dvs[64];
    int t = threadIdx.x, w = t >> 6, f = t & 63;
    int kb = blockIdx.x;
    if (t < 64) cnt[t] = 0;
    {
        const float4* W4 = (const float4*)W1;
        float4* Ws4 = (float4*)Ws;
#pragma unroll
        for (int j = 0; j < 4; j++) Ws4[t + 256 * j] = W4[t + 256 * j];
    }
    __syncthreads();
    int beg = bstart[kb], end = bstart[kb + 1];
    for (int e = beg + t; e < end; e += 256) atomicAdd(&cnt[staged[e] & 63], 1);
    __syncthreads();
    if (t < 64) {
        float dv = 1.0f / sqrtf((float)(cnt[t] + 1));  // + self-loop
        dvs[t] = dv;
        int node = kb * 64 + t;
        if (node < n) dinv[node] = dv;
    }
    __syncthreads();
    for (int sub = 0; sub < 4; sub++) {
        int rb = kb * 64 + sub * 16;
#pragma unroll
        for (int i = 0; i < 4; i++) {
            int r = rb + w * 4 + i;
            xs[w * 4 + i][f] = (r < n) ? X[(size_t)r * 64 + f] : 0.f;
        }
        __syncthreads();
        float acc0 = 0.f, acc1 = 0.f, acc2 = 0.f, acc3 = 0.f;
#pragma unroll
        for (int kq = 0; kq < 16; kq++) {
            float wv0 = Ws[(4 * kq + 0) * 64 + f];
            float wv1 = Ws[(4 * kq + 1) * 64 + f];
            float wv2 = Ws[(4 * kq + 2) * 64 + f];
            float wv3 = Ws[(4 * kq + 3) * 64 + f];
            float4 x0 = *(const float4*)&xs[w * 4 + 0][4 * kq];
            float4 x1 = *(const float4*)&xs[w * 4 + 1][4 * kq];
            float4 x2 = *(const float4*)&xs[w * 4 + 2][4 * kq];
            float4 x3 = *(const float4*)&xs[w * 4 + 3][4 * kq];
            acc0 += x0.x * wv0 + x0.y * wv1 + x0.z * wv2 + x0.w * wv3;
            acc1 += x1.x * wv0 + x1.y * wv1 + x1.z * wv2 + x1.w * wv3;
            acc2 += x2.x * wv0 + x2.y * wv1 + x2.z * wv2 + x2.w * wv3;
            acc3 += x3.x * wv0 + x3.y * wv1 + x3.z * wv2 + x3.w * wv3;
        }
        float av[4] = {acc0, acc1, acc2, acc3};
#pragma unroll
        for (int i = 0; i < 4; i++) {
            int r = rb + w * 4 + i;
            if (r < n) Y[(size_t)r * 64 + f] = f2bf(dvs[sub * 16 + w * 4 + i] * av[i]);
        }
        __syncthreads();
    }
}

// Layer-1 aggregate (edge-parallel, NATIVE int LDS atomics) + fused GEMM2.
// accL layout: feature f=4c+j of node dl at col m=16j+c (row stride 68).
__global__ __launch_bounds__(256) void k_agg1(const unsigned short* __restrict__ Yin,
                                              const float* __restrict__ dinv,
                                              const float* __restrict__ b1,
                                              const int* __restrict__ staged,
                                              const int* __restrict__ bstart,
                                              const float* __restrict__ W2,
                                              unsigned short* __restrict__ Yout, int n) {
    __shared__ int accL[64 * 68];   // 17408 B (int during stream, fp32 after)
    __shared__ float Ws[64 * 64];   // 16 KB, fm-swizzled rows of W2
    __shared__ float dvs[64];
    float* accF = (float*)accL;
    int t = threadIdx.x, w = t >> 6, l = t & 63;
    int kb = blockIdx.x;
    // zero acc (int4) + stage Ws (row m <- W2 row fm(m)) + dvs
    {
        int4* a4 = (int4*)accL;
        int4 z = make_int4(0, 0, 0, 0);
        for (int i = t; i < 64 * 17; i += 256) a4[i] = z;
        int m = t >> 2, seg = t & 3;
        int fm = ((m & 15) << 2) | (m >> 4);
        const float4* W24 = (const float4*)W2;
        float4* Ws4 = (float4*)Ws;
#pragma unroll
        for (int k = 0; k < 4; k++) Ws4[m * 16 + seg * 4 + k] = W24[fm * 16 + seg * 4 + k];
        if (t < 64) {
            int node = kb * 64 + t;
            dvs[t] = (node < n) ? dinv[node] : 0.f;
        }
    }
    __syncthreads();
    // ---- stream slab: slot S (16 threads) handles edges S*4+u per 64-window
    int beg = bstart[kb], end = bstart[kb + 1];
    int c = l & 15;
    int S = t >> 4;  // 0..15 across block
    const ushort4* Y4 = (const ushort4*)Yin;
    int eb = beg + S * 4;
    int pk[4];
#pragma unroll
    for (int u = 0; u < 4; u++) pk[u] = (eb + u < end) ? staged[eb + u] : -1;
    for (; eb < end;) {
        int en = eb + 64;
        int pn[4];
#pragma unroll
        for (int u = 0; u < 4; u++) pn[u] = (en + u < end) ? staged[en + u] : -1;
#pragma unroll
        for (int u = 0; u < 4; u++) {
            int p = pk[u];
            if (p >= 0) {
                int s = p >> 6, dl = p & 63;
                ushort4 v = Y4[(size_t)s * 16 + c];
                int* ap = &accL[dl * 68 + c];
                atomicAdd(ap + 0,  __float2int_rn(bf2f(v.x) * SCL));
                atomicAdd(ap + 16, __float2int_rn(bf2f(v.y) * SCL));
                atomicAdd(ap + 32, __float2int_rn(bf2f(v.z) * SCL));
                atomicAdd(ap + 48, __float2int_rn(bf2f(v.w) * SCL));
            }
        }
#pragma unroll
        for (int u = 0; u < 4; u++) pk[u] = pn[u];
        eb = en;
    }
    __syncthreads();
    // ---- Phase A: in-place int -> h' = dv * relu(dv*(acc+self) + b1)
    {
        int r = t >> 2, qd = t & 3;
        int node = kb * 64 + r;
        float dv = dvs[r];
        bool valid = node < n;
#pragma unroll
        for (int jj = 0; jj < 16; jj++) {
            int m = qd * 16 + jj;
            int fm = (jj << 2) | qd;   // ((m&15)<<2)|(m>>4)
            float aggv = (float)accL[r * 68 + m] * INVSCL;
            float self = valid ? bf2f(Yin[(size_t)node * 64 + fm]) : 0.f;
            float hv = fmaxf(dv * (aggv + self) + b1[fm], 0.f);
            accF[r * 68 + m] = dv * hv;   // 0 for invalid rows (dv=0,b? b1!=0..)
        }
        if (!valid) {
#pragma unroll
            for (int jj = 0; jj < 16; jj++) accF[r * 68 + qd * 16 + jj] = 0.f;
        }
    }
    __syncthreads();
    // ---- Phase B: GEMM2. wave w: rows w*16..+15; lane l = out feature.
    float acc2[16];
#pragma unroll
    for (int r = 0; r < 16; r++) acc2[r] = 0.f;
    for (int q = 0; q < 16; q++) {
        float wv0 = Ws[(4 * q + 0) * 64 + l];
        float wv1 = Ws[(4 * q + 1) * 64 + l];
        float wv2 = Ws[(4 * q + 2) * 64 + l];
        float wv3 = Ws[(4 * q + 3) * 64 + l];
#pragma unroll
        for (int r = 0; r < 16; r++) {
            float4 h4 = *(const float4*)&accF[(w * 16 + r) * 68 + 4 * q];
            acc2[r] += h4.x * wv0 + h4.y * wv1 + h4.z * wv2 + h4.w * wv3;
        }
    }
#pragma unroll
    for (int r = 0; r < 16; r++) {
        int node = kb * 64 + w * 16 + r;
        if (node < n) Yout[(size_t)node * 64 + l] = f2bf(acc2[r]);
    }
}

// Layer-2 aggregate (int LDS atomics) + mean folded into 8-way gpart atomics
// (782 blocks x 64 = 50k global atomics, R13-proven scale).
__global__ __launch_bounds__(256) void k_agg2(const unsigned short* __restrict__ Yin,
                                              const float* __restrict__ dinv,
                                              const float* __restrict__ b2,
                                              const int* __restrict__ staged,
                                              const int* __restrict__ bstart,
                                              float* __restrict__ gpart, int n) {
    __shared__ int accL[64 * 68];
    __shared__ float dvs[64];
    __shared__ float part[4][64];
    int t = threadIdx.x, w = t >> 6, l = t & 63;
    int kb = blockIdx.x;
    {
        int4* a4 = (int4*)accL;
        int4 z = make_int4(0, 0, 0, 0);
        for (int i = t; i < 64 * 17; i += 256) a4[i] = z;
        if (t < 64) {
            int node = kb * 64 + t;
            dvs[t] = (node < n) ? dinv[node] : 0.f;
        }
    }
    __syncthreads();
    int beg = bstart[kb], end = bstart[kb + 1];
    int c = l & 15;
    int S = t >> 4;
    const ushort4* Y4 = (const ushort4*)Yin;
    int eb = beg + S * 4;
    int pk[4];
#pragma unroll
    for (int u = 0; u < 4; u++) pk[u] = (eb + u < end) ? staged[eb + u] : -1;
    for (; eb < end;) {
        int en = eb + 64;
        int pn[4];
#pragma unroll
        for (int u = 0; u < 4; u++) pn[u] = (en + u < end) ? staged[en + u] : -1;
#pragma unroll
        for (int u = 0; u < 4; u++) {
            int p = pk[u];
            if (p >= 0) {
                int s = p >> 6, dl = p & 63;
                ushort4 v = Y4[(size_t)s * 16 + c];
                int* ap = &accL[dl * 68 + c];
                atomicAdd(ap + 0,  __float2int_rn(bf2f(v.x) * SCL));
                atomicAdd(ap + 16, __float2int_rn(bf2f(v.y) * SCL));
                atomicAdd(ap + 32, __float2int_rn(bf2f(v.z) * SCL));
                atomicAdd(ap + 48, __float2int_rn(bf2f(v.w) * SCL));
            }
        }
#pragma unroll
        for (int u = 0; u < 4; u++) pk[u] = pn[u];
        eb = en;
    }
    __syncthreads();
    int m = l;
    int fm = ((m & 15) << 2) | (m >> 4);
    float bb = b2[fm];
    float local = 0.f;
#pragma unroll
    for (int i = 0; i < 16; i++) {
        int r = w * 16 + i;
        int node = kb * 64 + r;
        if (node < n) {
            float dv = dvs[r];
            float aggv = (float)accL[r * 68 + m] * INVSCL;
            float self = bf2f(Yin[(size_t)node * 64 + fm]);
            local += fmaxf(dv * (aggv + self) + bb, 0.f);
        }
    }
    part[w][m] = local;
    __syncthreads();
    if (t < 64) {
        float tot = part[0][t] + part[1][t] + part[2][t] + part[3][t];
        int fm2 = ((t & 15) << 2) | (t >> 4);
        atomicAdd(&gpart[((kb & 7) << 6) + fm2], tot);
    }
}

__global__ void k_readout(const float* __restrict__ gpart, const float* __restrict__ Wr,
                          const float* __restrict__ br, float* __restrict__ out,
                          float invn) {
    __shared__ float gl[64];
    int t = threadIdx.x;
    if (t < 64) {
        float s = 0.f;
#pragma unroll
        for (int j = 0; j < 8; j++) s += gpart[j * 64 + t];
        gl[t] = s * invn;
    }
    __syncthreads();
    float acc = br[t];
#pragma unroll
    for (int k = 0; k < 64; k++) acc += gl[k] * Wr[k * 128 + t];
    out[t] = acc;
}

extern "C" void kernel_launch(void* const* d_in, const int* in_sizes, int n_in,
                              void* d_out, int out_size, void* d_ws, size_t ws_size,
                              hipStream_t stream) {
    const float* x  = (const float*)d_in[0];
    const int*   ei = (const int*)d_in[1];   // int32 on device (JAX x64 off)
    const float* W1 = (const float*)d_in[2];
    const float* b1 = (const float*)d_in[3];
    const float* W2 = (const float*)d_in[4];
    const float* b2 = (const float*)d_in[5];
    const float* Wr = (const float*)d_in[6];
    const float* br = (const float*)d_in[7];
    float* out = (float*)d_out;

    int n = in_sizes[0] / 64;   // 50000
    int E = in_sizes[1] / 2;    // 800000
    const int* src = ei;
    const int* dst = ei + E;

    int NB  = (n + 63) / 64;       // 782 buckets of 64 nodes
    int nch = (E + CH - 1) / CH;   // 196 chunks

    // workspace layout (~17 MB)
    char* p = (char*)d_ws;
    unsigned short* y1 = (unsigned short*)p; p += (size_t)n * 64 * sizeof(unsigned short);
    unsigned short* y2 = (unsigned short*)p; p += (size_t)n * 64 * sizeof(unsigned short);
    float* dinv = (float*)p;   p += (size_t)n * sizeof(float);
    float* gpart = (float*)p;  p += 512 * sizeof(float);
    int* staged = (int*)p;     p += (size_t)E * sizeof(int);
    int* histmat = (int*)p;    p += (size_t)nch * NB * sizeof(int);
    int* bstart = (int*)p;     p += (size_t)(NB + 1) * sizeof(int);

    k_bucket_hist<<<nch, 256, 0, stream>>>(dst, histmat, E, NB);
    k_scan<<<1, 1024, 0, stream>>>(histmat, bstart, gpart, NB, nch, E);
    k_bucket_scatter<<<nch, 256, 0, stream>>>(src, dst, histmat, bstart, staged, E, NB);
    k_dinv_gemm<<<NB, 256, 0, stream>>>(x, W1, staged, bstart, dinv, y1, n);
    k_agg1<<<NB, 256, 0, stream>>>(y1, dinv, b1, staged, bstart, W2, y2, n);
    k_agg2<<<NB, 256, 0, stream>>>(y2, dinv, b2, staged, bstart, gpart, n);
    k_readout<<<1, 128, 0, stream>>>(gpart, Wr, br, out, 1.0f / (float)n);
}